// Round 6
// baseline (74.347 us; speedup 1.0000x reference)
//
#include <hip/hip_runtime.h>

#define N_NODES 100000
#define E_EDGES 2000000
#define SPLIT_E 1800000   // top 10% of edges: 400k touches, P(node untouched) ~ e^-4 ~ 1.8%
#define CIN 16
#define EXH_FLOW 4.0f     // 0.0001 * 40000
#define TOP_E (E_EDGES - SPLIT_E)

// origin_data layout: (N, T=8, 3) f32; last timestep at n*24 + {21,22,23}
// = {concentration, people, size}

// Merged: node-init (threads [0, N)) + top-chunk scatter (threads [N, N+TOP_E)).
// No dependency between the halves: max_ord/settled pre-initialized by memset.
// Top chunk uses pure atomics (values unsettled here — R2 lesson) and marks
// touched nodes settled: their orders >= 2*SPLIT_E dominate all lower orders,
// so after this dispatch their max is FINAL. Same-value byte races benign.
__global__ void init_and_top_kernel(const float* __restrict__ origin,
                                    const int* __restrict__ src,
                                    const int* __restrict__ dst,
                                    float* __restrict__ out,
                                    float* __restrict__ conc_c,
                                    float* __restrict__ rsize_c,
                                    int* __restrict__ max_ord,
                                    unsigned char* __restrict__ settled) {
    int i = blockIdx.x * blockDim.x + threadIdx.x;
    if (i < N_NODES) {
        size_t base = (size_t)i * 24;
        float conc   = origin[base + 21];
        float people = origin[base + 22];
        float size   = origin[base + 23];
        float rs = 1.0f / size;
        out[i] = conc + EXH_FLOW * people * rs;
        conc_c[i]  = conc;
        rsize_c[i] = rs;
    } else {
        int e = SPLIT_E + (i - N_NODES);
        if (e >= E_EDGES) return;
        int s = src[e], d = dst[e];
        if (s != d) {
            atomicMax(&max_ord[s], 2 * e);
            atomicMax(&max_ord[d], 2 * e + 1);
            settled[s] = 1;
            settled[d] = 1;
        }
    }
}

// Main pass: coalesced x-stream (4 lanes/edge, one float4 each, shfl reduce)
// + scatter via the IMMUTABLE settled map (100 KB, read-only here -> L2-hot,
// never invalidated; the ~66k atomics hit a different array). Scatter work is
// spread across the lane quartet to shorten each lane's dependent chain:
//   q0: load src[e], handle s-side;  q1: load dst[e], handle d-side;
//   q2: store flow. Top-range edges skip (their endpoints are settled).
__global__ void fused_flow_scatter_kernel(const float4* __restrict__ xv,
                                          const float* __restrict__ w,
                                          const float* __restrict__ b,
                                          const int* __restrict__ src,
                                          const int* __restrict__ dst,
                                          const unsigned char* __restrict__ settled,
                                          float* __restrict__ flow,
                                          int* __restrict__ max_ord) {
    int tid = blockIdx.x * blockDim.x + threadIdx.x;   // over E*4 = 8M
    if (tid >= E_EDGES * 4) return;
    int q = tid & 3;
    int e = tid >> 2;
    float4 v  = xv[tid];                 // consecutive lanes -> consecutive 16B
    float4 wq = ((const float4*)w)[q];   // 64B total, L1 broadcast
    float p = v.x * wq.x + v.y * wq.y + v.z * wq.z + v.w * wq.w;
    p += __shfl_xor(p, 1);
    p += __shfl_xor(p, 2);               // all 4 lanes hold the full dot now
    // q0 lanes read src (16 consecutive ints -> 64B/wave), q1 lanes read dst.
    int my_idx = (q == 0) ? src[e] : ((q == 1) ? dst[e] : 0);
    int other  = __shfl_xor(my_idx, 1); // q0 gets d, q1 gets s
    if (q == 2) {
        flow[e] = p + b[0];              // 16 lanes/wave, contiguous 64B
    } else if (q == 0) {
        if (my_idx != other && !settled[my_idx])
            atomicMax(&max_ord[my_idx], 2 * e);
    } else if (q == 1) {
        if (my_idx != other && !settled[my_idx])
            atomicMax(&max_ord[my_idx], 2 * e + 1);
    }
}

// Per-node finalize: decode winning occurrence, gather its value.
__global__ void finalize_kernel(const int* __restrict__ src,
                                const float* __restrict__ flow,
                                const int* __restrict__ max_ord,
                                const float* __restrict__ conc_c,
                                const float* __restrict__ rsize_c,
                                float* __restrict__ out) {
    int n = blockIdx.x * blockDim.x + threadIdx.x;
    if (n >= N_NODES) return;
    int o = max_ord[n];
    if (o < 0) return;
    int e = o >> 1;
    float val = flow[e];
    float v;
    if ((o & 1) == 0) {
        v = val * conc_c[n] * rsize_c[n];            // src-side: src[e]==n
    } else {
        int s = src[e];
        v = val * conc_c[s] * rsize_c[n];            // dst-side
    }
    out[n] += v;
}

extern "C" void kernel_launch(void* const* d_in, const int* in_sizes, int n_in,
                              void* d_out, int out_size, void* d_ws, size_t ws_size,
                              hipStream_t stream) {
    const float* origin = (const float*)d_in[0];   // (N, 8, 3)
    const float* x      = (const float*)d_in[1];   // (E, 1, 16)
    const float* conv_w = (const float*)d_in[2];   // (1, 16, 1, 1)
    const float* conv_b = (const float*)d_in[3];   // (1,)
    const int*   eidx   = (const int*)d_in[4];     // (2, E)
    const int* src = eidx;
    const int* dst = eidx + E_EDGES;

    float* out  = (float*)d_out;          // [0, N): result; [N, N+E): flow
    float* flow = out + N_NODES;

    int*           max_ord = (int*)d_ws;                           // 400 KB
    float*         conc_c  = (float*)((char*)d_ws + 1 * 400 * 1024);
    float*         rsize_c = (float*)((char*)d_ws + 2 * 400 * 1024);
    unsigned char* settled = (unsigned char*)((char*)d_ws + 3 * 400 * 1024); // 100 KB

    // Table init via memset nodes (graph-capture-safe): -1 is bytewise 0xFF.
    hipMemsetAsync(max_ord, 0xFF, N_NODES * sizeof(int), stream);
    hipMemsetAsync(settled, 0x00, N_NODES, stream);

    const int BLK = 256;
    init_and_top_kernel<<<((N_NODES + TOP_E) + BLK - 1) / BLK, BLK, 0, stream>>>(
        origin, src, dst, out, conc_c, rsize_c, max_ord, settled);
    fused_flow_scatter_kernel<<<((E_EDGES * 4) + BLK - 1) / BLK, BLK, 0, stream>>>(
        (const float4*)x, conv_w, conv_b, src, dst, settled, flow, max_ord);
    finalize_kernel<<<(N_NODES + BLK - 1) / BLK, BLK, 0, stream>>>(
        src, flow, max_ord, conc_c, rsize_c, out);
}